// Round 8
// baseline (828.751 us; speedup 1.0000x reference)
//
#include <hip/hip_runtime.h>
#include <math.h>

#define F 256

// bucket geometry (reverted to 128-row buckets; 32-row was a bin_edges regression)
#define BKT_SHIFT 7
#define BKT_ROWS 128
#define BKT_CAP 8192      // LDS sort capacity (64 KB)
#define NB_MAX 1024
#define BIN_CHUNK 8192

typedef __attribute__((ext_vector_type(8))) short short8;
typedef __attribute__((ext_vector_type(4))) float f32x4;
typedef __attribute__((ext_vector_type(2))) int i32x2;
typedef __attribute__((ext_vector_type(4))) unsigned short u16x4;
typedef __attribute__((ext_vector_type(8))) unsigned short u16x8;

__device__ __forceinline__ unsigned short f2bf(float f) {
  union { float f; unsigned u; } v; v.f = f;
  unsigned r = (v.u + 0x7fffu + ((v.u >> 16) & 1u)) >> 16;
  return (unsigned short)r;
}
__device__ __forceinline__ float bf2f(unsigned short h) {
  union { unsigned u; float f; } v; v.u = ((unsigned)h) << 16;
  return v.f;
}

// ---- prep: blocks [0,256): W[k][n] -> Wt[n][k] bf16.
//            blocks [256,256+nxb): x fp32 -> xb bf16.
//            blocks [256+nxb,..): per-chunk bucket histogram -> hist_mat row
//            (no atomics, no memset needed).
__global__ void prep(const float* __restrict__ W, unsigned short* __restrict__ Wt,
                     const float* __restrict__ x, unsigned short* __restrict__ xb,
                     int NF, const int* __restrict__ rows,
                     int* __restrict__ hist_mat, int nxb, int E, int NB) {
  if (blockIdx.x < 256) {
    int idx = blockIdx.x * 256 + threadIdx.x;
    int k = idx >> 8, n = idx & 255;
    Wt[n * F + k] = f2bf(W[k * F + n]);
    return;
  }
  int xbid = blockIdx.x - 256;
  if (xbid < nxb) {
    int i0 = xbid * 2048 + threadIdx.x * 8;
    if (i0 + 8 <= NF) {
      f32x4 a = __builtin_nontemporal_load((const f32x4*)(x + i0));
      f32x4 b = __builtin_nontemporal_load((const f32x4*)(x + i0 + 4));
      u16x8 o;
      o[0] = f2bf(a.x); o[1] = f2bf(a.y); o[2] = f2bf(a.z); o[3] = f2bf(a.w);
      o[4] = f2bf(b.x); o[5] = f2bf(b.y); o[6] = f2bf(b.z); o[7] = f2bf(b.w);
      *(u16x8*)(xb + i0) = o;
    } else {
      for (int i = i0; i < NF; ++i) xb[i] = f2bf(x[i]);
    }
    return;
  }
  // ---- histogram chunk (sort path only) ----
  __shared__ int hist[NB_MAX];
  const int tid = threadIdx.x;
  const int c = xbid - nxb;
  const int e0 = c * BIN_CHUNK;
  for (int b = tid; b < NB; b += 256) hist[b] = 0;
  __syncthreads();
#pragma unroll
  for (int k = 0; k < BIN_CHUNK / 256; ++k) {
    int e = e0 + k * 256 + tid;
    if (e < E) atomicAdd(&hist[rows[e] >> BKT_SHIFT], 1);
  }
  __syncthreads();
  for (int b = tid; b < NB; b += 256) hist_mat[c * NB + b] = hist[b];
}

// ---- one block: 2D prefix of hist_mat. After this:
// hist_mat[c][b] = global base where chunk c's bucket-b edges go (exact).
// bbase[b] = bucket segment start; bbase[NB] = E; row_start[N] = E.
__global__ __launch_bounds__(1024) void scan_buckets(
    int* __restrict__ hm, int* __restrict__ bbase, int* __restrict__ row_start,
    int nch, int NB, int E, int N) {
  __shared__ int tot[1024];
  int t = threadIdx.x;
  int total_b = 0;
  if (t < NB) {            // exclusive prefix along chunks (each thread owns 1 bucket)
    int run = 0;
    for (int c = 0; c < nch; ++c) {
      int v = hm[c * NB + t];
      hm[c * NB + t] = run;
      run += v;
    }
    total_b = run;
  }
  tot[t] = (t < NB) ? total_b : 0;
  __syncthreads();
  for (int off = 1; off < 1024; off <<= 1) {
    int a = (t >= off) ? tot[t - off] : 0;
    __syncthreads();
    tot[t] += a;
    __syncthreads();
  }
  if (t < NB) {
    int ex = tot[t] - total_b;   // exclusive bucket prefix
    bbase[t] = ex;
    for (int c = 0; c < nch; ++c) hm[c * NB + t] += ex;
  }
  if (t == 0) { bbase[NB] = E; row_start[N] = E; }
}

// ---- single-pass binning scatter (no global atomics): block c starts its
// per-bucket cursors at hist_mat[c][*]. Packs (col | row_local<<20, val).
__global__ __launch_bounds__(512) void bin_edges(
    const int* __restrict__ rows, const int* __restrict__ cols,
    const float* __restrict__ vals, const int* __restrict__ hm,
    i32x2* __restrict__ etmp, int E, int NB) {
  __shared__ int cur[NB_MAX];
  const int tid = threadIdx.x;
  const int c = blockIdx.x;
  const int e0 = c * BIN_CHUNK;
  for (int b = tid; b < NB; b += 512) cur[b] = hm[c * NB + b];
  __syncthreads();
#pragma unroll
  for (int k = 0; k < BIN_CHUNK / 512; ++k) {
    int e = e0 + k * 512 + tid;
    if (e < E) {
      int r = rows[e];
      int b = r >> BKT_SHIFT;
      int pos = atomicAdd(&cur[b], 1);
      int cc = __builtin_nontemporal_load(&cols[e]);
      float v = __builtin_nontemporal_load(&vals[e]);
      etmp[pos] = (i32x2){cc | ((r & (BKT_ROWS - 1)) << 20), __float_as_int(v)};
    }
  }
}

// ---- per-bucket CSR finish: LDS hist -> scan -> writes row_start -> stable
// LDS scatter -> coalesced write of sorted segment. Reads etmp, writes edges
// (different buffers -> overflow branch scatters global-direct, still correct).
__global__ __launch_bounds__(512) void sort_bucket(
    const i32x2* __restrict__ etmp, const int* __restrict__ bbase,
    i32x2* __restrict__ edges, int* __restrict__ row_start, int N) {
  __shared__ int cur[BKT_ROWS];
  __shared__ int pre[BKT_ROWS];
  __shared__ i32x2 sorted[BKT_CAP];
  const int b = blockIdx.x;
  const int r0 = b << BKT_SHIFT;
  int nrows = N - r0; if (nrows > BKT_ROWS) nrows = BKT_ROWS;
  const int seg0 = bbase[b];
  const int cnt = bbase[b + 1] - seg0;
  const int tid = threadIdx.x;

  if (tid < BKT_ROWS) cur[tid] = 0;
  __syncthreads();
  for (int i = tid; i < cnt; i += 512)
    atomicAdd(&cur[(etmp[seg0 + i].x >> 20) & (BKT_ROWS - 1)], 1);
  __syncthreads();
  int myc = (tid < BKT_ROWS) ? cur[tid] : 0;
  __syncthreads();
  for (int off = 1; off < BKT_ROWS; off <<= 1) {
    int a = 0;
    if (tid < BKT_ROWS && tid >= off) a = cur[tid - off];
    __syncthreads();
    if (tid < BKT_ROWS) cur[tid] += a;
    __syncthreads();
  }
  if (tid < BKT_ROWS) {
    int ex = cur[tid] - myc;
    pre[tid] = ex;
    cur[tid] = ex;                         // running cursor
    if (tid < nrows) row_start[r0 + tid] = seg0 + ex;
  }
  __syncthreads();

  if (cnt <= BKT_CAP) {
    for (int i = tid; i < cnt; i += 512) {
      i32x2 w = etmp[seg0 + i];
      int rl = (w.x >> 20) & (BKT_ROWS - 1);
      int idx = atomicAdd(&cur[rl], 1);
      sorted[idx] = (i32x2){w.x & 0xFFFFF, w.y};
    }
    __syncthreads();
    for (int i = tid; i < cnt; i += 512)
      edges[seg0 + i] = sorted[i];
  } else {
    // overflow (statistically unreachable here): direct global scatter;
    // src etmp and dst edges are different buffers -> no in-place race.
    for (int i = tid; i < cnt; i += 512) {
      i32x2 w = etmp[seg0 + i];
      int rl = (w.x >> 20) & (BKT_ROWS - 1);
      int idx = atomicAdd(&cur[rl], 1);
      edges[seg0 + idx] = (i32x2){w.x & 0xFFFFF, w.y};
    }
  }
}

// ---- gather (bf16 x): one wave per row, wave-wide bulk edge load + readlane
// broadcast, 8-deep ping-pong x-loads. Output: bf16 support (sup16) if
// use16, else fp32 support (legacy). h0 blend fused either way.
__global__ __launch_bounds__(256) void gather_rows_bf16(
    const unsigned short* __restrict__ xb, const float* __restrict__ h0,
    const int* __restrict__ row_start, const i32x2* __restrict__ edges,
    float* __restrict__ outf32, unsigned short* __restrict__ sup16,
    const float* __restrict__ alpha_p, int N, int use16) {
  int gid = blockIdx.x * 256 + threadIdx.x;
  int r = gid >> 6;
  if (r >= N) return;
  int lane = threadIdx.x & 63;
  float alpha = *alpha_p;
  int s = row_start[r], e = row_start[r + 1];
  const unsigned short* xbl = xb + lane * 4;
  f32x4 acc0 = (f32x4){0.f, 0.f, 0.f, 0.f};
  f32x4 acc1 = (f32x4){0.f, 0.f, 0.f, 0.f};

#define GRP_LOAD8(XV, VV, JB)                                             \
  {                                                                       \
    _Pragma("unroll")                                                     \
    for (int k = 0; k < 8; ++k) {                                         \
      int col = __builtin_amdgcn_readlane(med.x, (JB) + k);               \
      VV[k] = __int_as_float(__builtin_amdgcn_readlane(med.y, (JB) + k)); \
      XV[k] = *(const u16x4*)(xbl + (size_t)col * F);                     \
    }                                                                     \
  }
#define GRP_FMA8(XV, VV)                                                  \
  {                                                                       \
    _Pragma("unroll")                                                     \
    for (int k = 0; k < 8; ++k) {                                         \
      f32x4& A = (k & 1) ? acc1 : acc0;                                   \
      A.x += VV[k] * bf2f(XV[k][0]);                                      \
      A.y += VV[k] * bf2f(XV[k][1]);                                      \
      A.z += VV[k] * bf2f(XV[k][2]);                                      \
      A.w += VV[k] * bf2f(XV[k][3]);                                      \
    }                                                                     \
  }

  while (s < e) {
    int cnt = e - s;
    if (cnt > 64) cnt = 64;
    i32x2 med;
    if (lane < cnt) med = edges[s + lane];
    else { med.x = 0; med.y = 0; }  // col 0, val 0 -> contributes 0
    u16x4 xA[8], xB[8];
    float vA[8], vB[8];
    int jb = 0;
    GRP_LOAD8(xA, vA, 0);
    while (true) {
      int jn = jb + 8;
      if (jn < cnt) GRP_LOAD8(xB, vB, jn);
      GRP_FMA8(xA, vA);
      jb = jn;
      if (jb >= cnt) break;
      jn = jb + 8;
      if (jn < cnt) GRP_LOAD8(xA, vA, jn);
      GRP_FMA8(xB, vB);
      jb = jn;
      if (jb >= cnt) break;  // REQUIRED: cnt%16==0 would re-run stale FMA(A)
    }
    s += cnt;
  }
#undef GRP_LOAD8
#undef GRP_FMA8

  f32x4 acc = acc0 + acc1;
  f32x4 b = __builtin_nontemporal_load((const f32x4*)(h0 + (size_t)r * F) + lane);
  float om = 1.0f - alpha;
  f32x4 o = om * acc + alpha * b;
  if (use16) {
    u16x4 ov;
    ov[0] = f2bf(o.x); ov[1] = f2bf(o.y); ov[2] = f2bf(o.z); ov[3] = f2bf(o.w);
    *(u16x4*)(sup16 + (size_t)r * F + lane * 4) = ov;
  } else {
    *((f32x4*)(outf32 + (size_t)r * F) + lane) = o;
  }
}

// ---- gather (fp32 x) fallback if ws can't hold xb ----
__global__ __launch_bounds__(256) void gather_rows_f32(
    const float* __restrict__ x, const float* __restrict__ h0,
    const int* __restrict__ row_start, const i32x2* __restrict__ edges,
    float* __restrict__ support, const float* __restrict__ alpha_p, int N) {
  int gid = blockIdx.x * 256 + threadIdx.x;
  int r = gid >> 6;
  if (r >= N) return;
  int lane = threadIdx.x & 63;
  float alpha = *alpha_p;
  int s = row_start[r], e = row_start[r + 1];
  f32x4 acc = (f32x4){0.f, 0.f, 0.f, 0.f};
  if (s < e) {
    i32x2 ed = __builtin_nontemporal_load(&edges[s]);
    f32x4 xv = *((const f32x4*)(x + (size_t)ed.x * F) + lane);
    for (int j = s; j < e; ++j) {
      i32x2 cur = ed;
      f32x4 xc = xv;
      if (j + 1 < e) {
        ed = __builtin_nontemporal_load(&edges[j + 1]);
        xv = *((const f32x4*)(x + (size_t)ed.x * F) + lane);
      }
      float v = __int_as_float(cur.y);
      acc += v * xc;
    }
  }
  f32x4 b = __builtin_nontemporal_load((const f32x4*)(h0 + (size_t)r * F) + lane);
  float om = 1.0f - alpha;
  f32x4 o = om * acc + alpha * b;
  *((f32x4*)(support + (size_t)r * F) + lane) = o;
}

// ---- GEMM + epilogue: out = theta*(support@W) + (1-theta)*support ----
// use16: support arrives as bf16 (sup16) -> LDS stage is a straight copy.
// else: support fp32 (may alias out; tile fully staged before writes).
__global__ __launch_bounds__(256) void gemm_epilogue(
    const float* support, const unsigned short* __restrict__ sup16,
    const unsigned short* __restrict__ Wt, float* out,
    const float* __restrict__ lamda_p, const int* __restrict__ l_p,
    int N, int use16) {
  __shared__ unsigned short sup[64][264];  // +8 pad: 2-way bank alias (free)

  const float theta = logf(*lamda_p / (float)(*l_p) + 1.0f);
  const float one_m_t = 1.0f - theta;

  const int m0 = blockIdx.x * 64;
  const int t = threadIdx.x;

  if (use16) {
#pragma unroll
    for (int i = 0; i < 8; ++i) {
      int g = t + i * 256;
      int row = g >> 5, c8 = g & 31;
      int g_row = m0 + row;
      u16x8 v = (u16x8){0, 0, 0, 0, 0, 0, 0, 0};
      if (g_row < N)
        v = *(const u16x8*)(sup16 + (size_t)g_row * F + c8 * 8);
      *(u16x8*)&sup[row][c8 << 3] = v;
    }
  } else {
#pragma unroll
    for (int i = 0; i < 16; ++i) {
      int f = t + i * 256;
      int row = f >> 6, c4 = f & 63;
      int g_row = m0 + row;
      f32x4 a = (f32x4){0.f, 0.f, 0.f, 0.f};
      if (g_row < N)
        a = __builtin_nontemporal_load((const f32x4*)(support + (size_t)g_row * F) + c4);
      unsigned short* p = &sup[row][c4 << 2];
      p[0] = f2bf(a.x); p[1] = f2bf(a.y); p[2] = f2bf(a.z); p[3] = f2bf(a.w);
    }
  }
  __syncthreads();

  const int wave = t >> 6, lane = t & 63;
  const int quad = lane >> 4, lcol = lane & 15;
  const int mrow = wave * 16;

  f32x4 acc[16];
#pragma unroll
  for (int n = 0; n < 16; ++n) acc[n] = (f32x4){0.f, 0.f, 0.f, 0.f};

#pragma unroll
  for (int k = 0; k < 8; ++k) {
    short8 afrag = *(const short8*)&sup[mrow + lcol][k * 32 + quad * 8];
#pragma unroll
    for (int n = 0; n < 16; ++n) {
      short8 bfrag = *(const short8*)&Wt[(size_t)(n * 16 + lcol) * F + k * 32 + quad * 8];
      acc[n] = __builtin_amdgcn_mfma_f32_16x16x32_bf16(afrag, bfrag, acc[n], 0, 0, 0);
    }
  }

#pragma unroll
  for (int n = 0; n < 16; ++n) {
#pragma unroll
    for (int r = 0; r < 4; ++r) {
      int lrow = mrow + quad * 4 + r;
      int col = n * 16 + lcol;
      int g_row = m0 + lrow;
      if (g_row < N) {
        float s = bf2f(sup[lrow][col]);
        __builtin_nontemporal_store(theta * acc[n][r] + one_m_t * s,
                                    &out[(size_t)g_row * F + col]);
      }
    }
  }
}

// ========================= fallback CSR path =========================
__global__ void hist_rows(const int* __restrict__ rows, int* counts, int E) {
  int e = blockIdx.x * 256 + threadIdx.x;
  if (e < E) atomicAdd(&counts[__builtin_nontemporal_load(&rows[e])], 1);
}

__global__ void scan1(const int* __restrict__ counts, int* row_start, int* blk, int N) {
  __shared__ int tmp[256];
  int t = threadIdx.x;
  int i = blockIdx.x * 256 + t;
  int v = (i < N) ? counts[i] : 0;
  tmp[t] = v;
  __syncthreads();
#pragma unroll
  for (int off = 1; off < 256; off <<= 1) {
    int a = (t >= off) ? tmp[t - off] : 0;
    __syncthreads();
    tmp[t] += a;
    __syncthreads();
  }
  if (i < N) row_start[i] = tmp[t] - v;
  if (t == 255) blk[blockIdx.x] = tmp[255];
}

__global__ void scan2(int* blk, int NB) {
  __shared__ int tmp[512];
  int t = threadIdx.x;
  int v = (t < NB) ? blk[t] : 0;
  tmp[t] = v;
  __syncthreads();
#pragma unroll
  for (int off = 1; off < 512; off <<= 1) {
    int a = (t >= off) ? tmp[t - off] : 0;
    __syncthreads();
    tmp[t] += a;
    __syncthreads();
  }
  if (t < NB) blk[t] = tmp[t] - v;
}

__global__ void scan3(const int* __restrict__ counts, int* row_start,
                      const int* __restrict__ blk, int* fill_ptr, int N) {
  int i = blockIdx.x * 256 + threadIdx.x;
  if (i >= N) return;
  int rs = row_start[i] + blk[i >> 8];
  row_start[i] = rs;
  fill_ptr[i] = rs;
  if (i == N - 1) row_start[N] = rs + counts[i];
}

__global__ void fill_csr(const int* __restrict__ rows, const int* __restrict__ cols,
                         const float* __restrict__ vals, int* fill_ptr,
                         int2* __restrict__ edges, int E) {
  int e = blockIdx.x * 256 + threadIdx.x;
  if (e >= E) return;
  int r = __builtin_nontemporal_load(&rows[e]);
  int c = __builtin_nontemporal_load(&cols[e]);
  float v = __builtin_nontemporal_load(&vals[e]);
  int pos = atomicAdd(&fill_ptr[r], 1);
  edges[pos] = make_int2(c, __float_as_int(v));
}

extern "C" void kernel_launch(void* const* d_in, const int* in_sizes, int n_in,
                              void* d_out, int out_size, void* d_ws, size_t ws_size,
                              hipStream_t stream) {
  const float* x     = (const float*)d_in[0];
  const int*   rows  = (const int*)d_in[1];
  const int*   cols  = (const int*)d_in[2];
  const float* vals  = (const float*)d_in[3];
  const float* h0    = (const float*)d_in[4];
  const float* W     = (const float*)d_in[5];
  const float* lamda = (const float*)d_in[6];
  const float* alpha = (const float*)d_in[7];
  const int*   lp    = (const int*)d_in[8];

  const int E = in_sizes[1];
  const int N = in_sizes[0] / F;
  const int NF = N * F;
  const int NB = (N + BKT_ROWS - 1) >> BKT_SHIFT;
  const int bchunks = (E + BIN_CHUNK - 1) / BIN_CHUNK;

  // ---- workspace layout (256B aligned regions) ----
  size_t off = 0;
  auto take = [&](size_t bytes) { size_t o = off; off += (bytes + 255) & ~(size_t)255; return o; };
  char* ws = (char*)d_ws;
  unsigned short* Wt  = (unsigned short*)(ws + take((size_t)F * F * 2));
  int* counts    = (int*)(ws + take((size_t)N * 4));          // fallback only
  int* row_start = (int*)(ws + take((size_t)(N + 1) * 4));    // shared
  int* fill_ptr  = (int*)(ws + take((size_t)N * 4));          // fallback only
  int* blk       = (int*)(ws + take(4096));                   // fallback only
  int* bbase     = (int*)(ws + take((size_t)(NB_MAX + 1) * 4));
  int* hist_mat  = (int*)(ws + take((size_t)bchunks * NB * 4));
  i32x2* edges   = (i32x2*)(ws + take((size_t)E * 8));
  unsigned short* xb = (unsigned short*)(ws + take((size_t)NF * 2));
  const int use_bf16 = (off <= ws_size);
  unsigned short* sup16 = (unsigned short*)(ws + take((size_t)NF * 2));
  const int use_sup16 = (off <= ws_size);

  float* out = (float*)d_out;

  // sort path: bf16 x, 20-bit cols, NB fits LDS hist/scan, out holds etmp scratch
  const int use_sort = use_bf16 && (E > 0) && (N <= (1 << 20)) && (NB <= NB_MAX) &&
                       ((size_t)E * 8 <= (size_t)out_size);

  int nxb = use_bf16 ? (NF + 2047) / 2048 : 0;
  int eb = (E + 255) / 256;
  int nb = (N + 255) / 256;  // must be <= 512 for scan2 (N=100000 -> 391)

  if (use_sort) {
    i32x2* etmp = (i32x2*)out;  // out as binning scratch (consumed by sort_bucket)
    prep<<<256 + nxb + bchunks, 256, 0, stream>>>(W, Wt, x, xb, NF, rows,
                                                  hist_mat, nxb, E, NB);
    scan_buckets<<<1, 1024, 0, stream>>>(hist_mat, bbase, row_start, bchunks, NB, E, N);
    bin_edges<<<bchunks, 512, 0, stream>>>(rows, cols, vals, hist_mat, etmp, E, NB);
    sort_bucket<<<NB, 512, 0, stream>>>(etmp, bbase, edges, row_start, N);
    int gather_blocks = (N * 64 + 255) / 256;
    gather_rows_bf16<<<gather_blocks, 256, 0, stream>>>(
        xb, h0, row_start, edges, out, sup16, alpha, N, use_sup16);
    gemm_epilogue<<<(N + 63) / 64, 256, 0, stream>>>(
        out, sup16, Wt, out, lamda, lp, N, use_sup16);
  } else {
    prep<<<256 + nxb, 256, 0, stream>>>(W, Wt, x, xb, NF, rows,
                                        hist_mat, nxb, E, 0);
    hipMemsetAsync(counts, 0, (size_t)N * sizeof(int), stream);
    hist_rows<<<eb, 256, 0, stream>>>(rows, counts, E);
    scan1<<<nb, 256, 0, stream>>>(counts, row_start, blk, N);
    scan2<<<1, 512, 0, stream>>>(blk, nb);
    scan3<<<nb, 256, 0, stream>>>(counts, row_start, blk, fill_ptr, N);
    fill_csr<<<eb, 256, 0, stream>>>(rows, cols, vals, fill_ptr, (int2*)edges, E);
    int gather_blocks = (N * 64 + 255) / 256;
    if (use_bf16) {
      gather_rows_bf16<<<gather_blocks, 256, 0, stream>>>(
          xb, h0, row_start, edges, out, sup16, alpha, N, 0);
    } else {
      gather_rows_f32<<<gather_blocks, 256, 0, stream>>>(x, h0, row_start, edges,
                                                         out, alpha, N);
    }
    gemm_epilogue<<<(N + 63) / 64, 256, 0, stream>>>(
        out, sup16, Wt, out, lamda, lp, N, 0);
  }
}